// Round 10
// baseline (165.551 us; speedup 1.0000x reference)
//
#include <hip/hip_runtime.h>

#define BB 4
#define NN 2048
#define FF 128
#define NP 2176  // padded WhT row stride in shorts: 4352 B = 17*256 -> L2 channel step 1
#define ALPHA 0.2f
#define NEG_BIG -9000000000000000.0f
#define SHIFT_C 16.0f  // exp(x-16): x=LR(f1+f2) bounded ~|10|; masked -> exp(-9e15)=0

typedef short bf16x8 __attribute__((ext_vector_type(8)));
typedef float f32x4 __attribute__((ext_vector_type(4)));

__device__ inline short f2bf(float f) {  // RNE float -> bf16 bits
    union { float f; unsigned u; } v; v.f = f;
    unsigned r = (v.u + 0x7FFFu + ((v.u >> 16) & 1u)) >> 16;
    return (short)r;
}
__device__ inline float bf2f(short s) {
    union { float f; unsigned u; } v;
    v.u = ((unsigned)(unsigned short)s) << 16;
    return v.f;
}

// ---------------------------------------------------------------------------
// k_pack: adjp[i][w] = bitmask of adj[i][w*32 .. w*32+31] (row stride 256 B).
// 1 wave per row, 4 rows per 256-thread block, grid 512.
// ---------------------------------------------------------------------------
__global__ __launch_bounds__(256) void k_pack(const int* __restrict__ adj,
                                              unsigned* __restrict__ adjp) {
    int w = threadIdx.x >> 6, lane = threadIdx.x & 63;
    int row = blockIdx.x * 4 + w;
    const int* ar = adj + (size_t)row * NN;
    for (int it = 0; it < 32; ++it) {
        int v = ar[it * 64 + lane];
        unsigned long long mask = __ballot(v > 0);
        if (lane == 0) adjp[row * 64 + it * 2] = (unsigned)mask;
        if (lane == 1) adjp[row * 64 + it * 2 + 1] = (unsigned)(mask >> 32);
    }
}

// ---------------------------------------------------------------------------
// k_wh: round-7 body transcribed to 16-row blocks (grid 512 -> 2 blocks/CU,
// fixes 1-wave/SIMD latency exposure). Per thread: 2 rows x 4 cols.
// Stores split-bf16 transposed with PADDED stride NP.
// ---------------------------------------------------------------------------
__global__ __launch_bounds__(256) void k_wh(const float* __restrict__ h,
                                            const float* __restrict__ W,
                                            const float* __restrict__ a,
                                            short* __restrict__ WhHiT,
                                            short* __restrict__ WhLoT,
                                            float* __restrict__ f1,
                                            float* __restrict__ f2) {
    __shared__ float Wa[2 * FF];
    __shared__ float hs[16 * 128];  // 8 KB
    int tid = threadIdx.x;
    int r0 = blockIdx.x * 16;

    // ---- Wa = [W@a1 ; W@a2] (verbatim round-7) ----
    {
        int fin = tid & 127;
        const float* av = (tid < 128) ? a : (a + FF);
        const float* wr = W + (size_t)fin * FF;
        float s = 0.f;
        for (int o = 0; o < FF; o += 4) {
            float4 wv = *(const float4*)(wr + o);
            float4 avv = *(const float4*)(av + o);
            s += wv.x * avv.x + wv.y * avv.y + wv.z * avv.z + wv.w * avv.w;
        }
        Wa[(tid < 128 ? 0 : FF) + fin] = s;
    }
    // ---- hs staging: 16 rows ----
    {
        const float4* src = (const float4*)(h + (size_t)r0 * FF);
        float4* dst = (float4*)hs;
        dst[tid] = src[tid];
        dst[256 + tid] = src[256 + tid];
    }
    __syncthreads();

    // ---- f1/f2: wave w handles rows w*4..w*4+3 ----
    {
        int w = tid >> 6, lane = tid & 63;
        float wa1_0 = Wa[lane], wa1_1 = Wa[lane + 64];
        float wa2_0 = Wa[FF + lane], wa2_1 = Wa[FF + lane + 64];
        for (int rr = 0; rr < 4; ++rr) {
            int rloc = w * 4 + rr;
            int row = r0 + rloc;
            float x0 = hs[rloc * FF + lane], x1 = hs[rloc * FF + lane + 64];
            float s1 = x0 * wa1_0 + x1 * wa1_1;
            float s2 = x0 * wa2_0 + x1 * wa2_1;
#pragma unroll
            for (int m = 32; m >= 1; m >>= 1) {
                s1 += __shfl_xor(s1, m, 64);
                s2 += __shfl_xor(s2, m, 64);
            }
            if (lane == 0) { f1[row] = s1; f2[row] = s2; }
        }
    }

    // ---- GEMM: thread = rows rg*2..rg*2+1 x cols f4..f4+3 ----
    int f4 = (tid & 31) * 4;
    int rg = tid >> 5;  // 0..7
    float acc[2][4];
#pragma unroll
    for (int rr = 0; rr < 2; ++rr)
#pragma unroll
        for (int cc = 0; cc < 4; ++cc) acc[rr][cc] = 0.f;

    for (int k0 = 0; k0 < FF; k0 += 4) {
        float4 wv[4];
#pragma unroll
        for (int kk = 0; kk < 4; ++kk)
            wv[kk] = *(const float4*)(W + (size_t)(k0 + kk) * FF + f4);
        float4 hv[2];
#pragma unroll
        for (int rr = 0; rr < 2; ++rr)
            hv[rr] = *(const float4*)(hs + (rg * 2 + rr) * FF + k0);
#pragma unroll
        for (int rr = 0; rr < 2; ++rr) {
            float hk[4] = {hv[rr].x, hv[rr].y, hv[rr].z, hv[rr].w};
#pragma unroll
            for (int kk = 0; kk < 4; ++kk) {
                acc[rr][0] += hk[kk] * wv[kk].x;
                acc[rr][1] += hk[kk] * wv[kk].y;
                acc[rr][2] += hk[kk] * wv[kk].z;
                acc[rr][3] += hk[kk] * wv[kk].w;
            }
        }
    }
    int rloc = r0 + rg * 2;
    int b = rloc >> 11;
    int j = rloc & (NN - 1);  // even; rows j, j+1 (same batch: 2048%16==0)
#pragma unroll
    for (int cc = 0; cc < 4; ++cc) {
        float v0 = acc[0][cc], v1 = acc[1][cc];
        short h0 = f2bf(v0), h1 = f2bf(v1);
        short l0 = f2bf(v0 - bf2f(h0)), l1 = f2bf(v1 - bf2f(h1));
        size_t off = (size_t)(b * FF + f4 + cc) * NP + j;
        *(short2*)(WhHiT + off) = make_short2(h0, h1);
        *(short2*)(WhLoT + off) = make_short2(l0, l1);
    }
}

// ---------------------------------------------------------------------------
// k_attn: round-9 structure; changes: (a) B-frag loads use padded NP stride
// (16 lines -> 16 L2 channels instead of 1), (b) adj via packed bitmask
// preloaded into 2 int4 per wave (row stride 256 B, 32x less volume).
// ---------------------------------------------------------------------------
__global__ __launch_bounds__(512, 4) void k_attn(const short* __restrict__ WhHiT,
                                                 const short* __restrict__ WhLoT,
                                                 const unsigned* __restrict__ adjp,
                                                 const float* __restrict__ f1,
                                                 const float* __restrict__ f2,
                                                 float* __restrict__ out) {
    __shared__ float obuf[4][2048];  // 32 KB
    __shared__ float row_s[8][16];
    __shared__ float row_inv[16];

    int tid = threadIdx.x;
    int b = blockIdx.x >> 7;           // 0..3
    int i0 = (blockIdx.x & 127) * 16;  // row-tile base
    int w = tid >> 6, lane = tid & 63; // w in 0..7

    const float* f2b = f2 + b * NN;

    int r_a = lane & 15;
    int kg = lane >> 4;
    int i = i0 + r_a;
    float f1i = f1[b * NN + i];
    const short* baseH = WhHiT + ((size_t)b * FF + r_a) * NP;
    const short* baseL = WhLoT + ((size_t)b * FF + r_a) * NP;

    // preload this wave's full adj-bit range: words w*8 .. w*8+7 of row i
    const int4* aprow = (const int4*)(adjp + (size_t)i * 64);
    int4 pw0 = aprow[w * 2];
    int4 pw1 = aprow[w * 2 + 1];
    unsigned wordv[8] = {(unsigned)pw0.x, (unsigned)pw0.y, (unsigned)pw0.z, (unsigned)pw0.w,
                         (unsigned)pw1.x, (unsigned)pw1.y, (unsigned)pw1.z, (unsigned)pw1.w};

    f32x4 acc[8];
#pragma unroll
    for (int n = 0; n < 8; ++n)
#pragma unroll
        for (int q = 0; q < 4; ++q) acc[n][q] = 0.f;
    float sp = 0.f;

    // prefetch c=0 f2
    int jb0 = w * 256 + kg * 8;
    float4 pq0 = *(const float4*)(f2b + jb0);
    float4 pq1 = *(const float4*)(f2b + jb0 + 4);

#pragma unroll
    for (int c = 0; c < 8; ++c) {
        int jb = w * 256 + c * 32 + kg * 8;
        float4 q0 = pq0, q1 = pq1;
        // prefetch next-iter f2 (dummy wrap at c==7)
        int jb_n = w * 256 + ((c + 1) & 7) * 32 + kg * 8;
        pq0 = *(const float4*)(f2b + jb_n);
        pq1 = *(const float4*)(f2b + jb_n + 4);

        unsigned word = wordv[c] >> (kg * 8);
        float qv[8] = {q0.x, q0.y, q0.z, q0.w, q1.x, q1.y, q1.z, q1.w};
        bf16x8 afrag;
#pragma unroll
        for (int t = 0; t < 8; ++t) {
            float x = f1i + qv[t];
            x = x > 0.f ? x : ALPHA * x;
            x = ((word >> t) & 1u) ? x : NEG_BIG;
            short pb = f2bf(__expf(x - SHIFT_C));
            sp += bf2f(pb);
            afrag[t] = pb;
        }

        const short* bh = baseH + jb;
        const short* bl = baseL + jb;
#pragma unroll
        for (int n = 0; n < 8; ++n) {
            bf16x8 fh = *(const bf16x8*)(bh + (size_t)n * 16 * NP);
            acc[n] = __builtin_amdgcn_mfma_f32_16x16x32_bf16(afrag, fh, acc[n], 0, 0, 0);
            bf16x8 fl = *(const bf16x8*)(bl + (size_t)n * 16 * NP);
            acc[n] = __builtin_amdgcn_mfma_f32_16x16x32_bf16(afrag, fl, acc[n], 0, 0, 0);
        }
    }

    // row sums: lanes {l, l+16, l+32, l+48} share row l&15
    sp += __shfl_xor(sp, 16, 64);
    sp += __shfl_xor(sp, 32, 64);
    if (lane < 16) row_s[w][lane] = sp;

    // ---- staged tree reduce of 8 wave-partials through obuf[0..3] ----
    if (w >= 4) {
#pragma unroll
        for (int n = 0; n < 8; ++n)
#pragma unroll
            for (int q = 0; q < 4; ++q)
                obuf[w - 4][(kg * 4 + q) * FF + n * 16 + r_a] = acc[n][q];
    }
    __syncthreads();
    if (tid < 16)
        row_inv[tid] = 1.0f / (row_s[0][tid] + row_s[1][tid] + row_s[2][tid] + row_s[3][tid] +
                               row_s[4][tid] + row_s[5][tid] + row_s[6][tid] + row_s[7][tid]);
    if (w < 4) {
#pragma unroll
        for (int n = 0; n < 8; ++n)
#pragma unroll
            for (int q = 0; q < 4; ++q)
                acc[n][q] += obuf[w][(kg * 4 + q) * FF + n * 16 + r_a];
    }
    __syncthreads();
    if (w == 2 || w == 3) {
#pragma unroll
        for (int n = 0; n < 8; ++n)
#pragma unroll
            for (int q = 0; q < 4; ++q)
                obuf[w - 2][(kg * 4 + q) * FF + n * 16 + r_a] = acc[n][q];
    }
    __syncthreads();
    if (w < 2) {
#pragma unroll
        for (int n = 0; n < 8; ++n)
#pragma unroll
            for (int q = 0; q < 4; ++q)
                acc[n][q] += obuf[w][(kg * 4 + q) * FF + n * 16 + r_a];
    }
    __syncthreads();
    if (w == 1) {
#pragma unroll
        for (int n = 0; n < 8; ++n)
#pragma unroll
            for (int q = 0; q < 4; ++q)
                obuf[1][(kg * 4 + q) * FF + n * 16 + r_a] = acc[n][q];
    }
    __syncthreads();
    if (w == 0) {
#pragma unroll
        for (int n = 0; n < 8; ++n)
#pragma unroll
            for (int q = 0; q < 4; ++q) {
                int o = (kg * 4 + q) * FF + n * 16 + r_a;
                obuf[0][o] = acc[n][q] + obuf[1][o];
            }
    }
    __syncthreads();

    // ---- epilogue: normalize + store (all 512 threads, one float4 each) ----
    {
        int e = tid * 4;  // 0..2044
        int row = e >> 7;
        float inv = row_inv[row];
        float4 v = *(const float4*)&obuf[0][e];
        float4 o;
        o.x = v.x * inv; o.y = v.y * inv; o.z = v.z * inv; o.w = v.w * inv;
        *(float4*)(out + ((size_t)b * NN + i0 + row) * FF + (e & 127)) = o;
    }
}

// ---------------------------------------------------------------------------
extern "C" void kernel_launch(void* const* d_in, const int* in_sizes, int n_in,
                              void* d_out, int out_size, void* d_ws, size_t ws_size,
                              hipStream_t stream) {
    const float* h   = (const float*)d_in[0];
    const int*   adj = (const int*)d_in[1];
    const float* W   = (const float*)d_in[2];
    const float* a   = (const float*)d_in[3];
    float* out = (float*)d_out;

    short* WhHiT = (short*)d_ws;                          // 4*128*2176 shorts = 2.23 MB
    short* WhLoT = WhHiT + (size_t)BB * FF * NP;          // 2.23 MB
    float* f1 = (float*)(WhLoT + (size_t)BB * FF * NP);   // 32 KB
    float* f2 = f1 + (size_t)BB * NN;                     // 32 KB
    unsigned* adjp = (unsigned*)(f2 + (size_t)BB * NN);   // 512 KB  (total ~4.8 MB)

    k_pack<<<NN / 4, 256, 0, stream>>>(adj, adjp);
    k_wh<<<(BB * NN) / 16, 256, 0, stream>>>(h, W, a, WhHiT, WhLoT, f1, f2);
    k_attn<<<BB * (NN / 16), 512, 0, stream>>>(WhHiT, WhLoT, adjp, f1, f2, out);
}